// Round 11
// baseline (1274.925 us; speedup 1.0000x reference)
//
#include <hip/hip_runtime.h>
#include <type_traits>
#include <utility>

// GroupQueryAttention on MI355X (gfx950), bf16 MFMA pipeline.
// B=2, Lq=Lk=2048, D_MODEL=1024, H=G=8, DEPTH=128.

using u16 = unsigned short;

typedef float f32x4 __attribute__((ext_vector_type(4)));
typedef short short8 __attribute__((ext_vector_type(8)));
typedef __bf16 bf16x8 __attribute__((ext_vector_type(8)));

#define DEV __device__ __forceinline__

// ---- MFMA wrapper: hedge the builtin's operand type (short8 vs bf16x8) ----
template <typename V, typename = void> struct MfmaTakes : std::false_type {};
template <typename V>
struct MfmaTakes<V, std::void_t<decltype(__builtin_amdgcn_mfma_f32_16x16x32_bf16(
    std::declval<V>(), std::declval<V>(), std::declval<f32x4>(), 0, 0, 0))>>
    : std::true_type {};
using mfma_ab = std::conditional_t<MfmaTakes<short8>::value, short8, bf16x8>;
static_assert(sizeof(mfma_ab) == 16, "mfma operand must be 4 VGPRs");

DEV f32x4 mfma16x16(short8 a, short8 b, f32x4 c) {
  return __builtin_amdgcn_mfma_f32_16x16x32_bf16(
      __builtin_bit_cast(mfma_ab, a), __builtin_bit_cast(mfma_ab, b), c, 0, 0, 0);
}

// ---- bf16 <-> f32 helpers (RNE) ----
DEV u16 f2b(float f) {
  unsigned u = __float_as_uint(f);
  u += 0x7fffu + ((u >> 16) & 1u);
  return (u16)(u >> 16);
}
DEV float b2f(u16 h) { return __uint_as_float(((unsigned)h) << 16); }

DEV short8 ld8(const u16* p) { return *reinterpret_cast<const short8*>(p); }
DEV void st8(u16* p, short8 v) { *reinterpret_cast<short8*>(p) = v; }

// ---- fp32 -> bf16 conversion (4 elems/thread) ----
__global__ __launch_bounds__(256) void k_cvt(const float* __restrict__ src,
                                             u16* __restrict__ dst, int n4) {
  int i = blockIdx.x * 256 + threadIdx.x;
  if (i >= n4) return;
  float4 v = reinterpret_cast<const float4*>(src)[i];
  unsigned long long r = (unsigned long long)f2b(v.x) |
                         ((unsigned long long)f2b(v.y) << 16) |
                         ((unsigned long long)f2b(v.z) << 32) |
                         ((unsigned long long)f2b(v.w) << 48);
  reinterpret_cast<unsigned long long*>(dst)[i] = r;
}

// ---- bf16 NT GEMM: C[M][N] = A[M][K] * B[N][K]^T, fp32 acc ----
// A may be bf16 (u16) or fp32 (converted in staging).
template <typename AT, typename OutT>
__global__ __launch_bounds__(256) void k_gemm_nt(const AT* __restrict__ A,
                                                 const u16* __restrict__ Bm,
                                                 OutT* __restrict__ C,
                                                 int M, int N, int K) {
  __shared__ __align__(16) u16 As[128][40];
  __shared__ __align__(16) u16 Bs[128][40];
  const int tid = threadIdx.x, lane = tid & 63, w = tid >> 6;
  const int lr = lane & 15, lg = lane >> 4;
  const int wr = w >> 1, wc = w & 1;
  const int m0 = blockIdx.y * 128, n0 = blockIdx.x * 128;

  f32x4 acc[4][4];
#pragma unroll
  for (int mi = 0; mi < 4; ++mi)
#pragma unroll
    for (int ni = 0; ni < 4; ++ni) acc[mi][ni] = f32x4{0.f, 0.f, 0.f, 0.f};

  for (int k0 = 0; k0 < K; k0 += 32) {
#pragma unroll
    for (int i = 0; i < 2; ++i) {   // 512 16B-chunks per tile, 2 per thread
      int c = tid + i * 256;
      int r = c >> 2, j = c & 3;
      short8 va;
      if constexpr (std::is_same_v<AT, float>) {
        const float* ap = A + (size_t)(m0 + r) * K + k0 + j * 8;
        float4 f0 = *reinterpret_cast<const float4*>(ap);
        float4 f1 = *reinterpret_cast<const float4*>(ap + 4);
        va = short8{(short)f2b(f0.x), (short)f2b(f0.y), (short)f2b(f0.z), (short)f2b(f0.w),
                    (short)f2b(f1.x), (short)f2b(f1.y), (short)f2b(f1.z), (short)f2b(f1.w)};
      } else {
        va = ld8(A + (size_t)(m0 + r) * K + k0 + j * 8);
      }
      short8 vb = ld8(Bm + (size_t)(n0 + r) * K + k0 + j * 8);
      st8(&As[r][j * 8], va);
      st8(&Bs[r][j * 8], vb);
    }
    __syncthreads();
    short8 af[4], bf[4];
#pragma unroll
    for (int mi = 0; mi < 4; ++mi) af[mi] = ld8(&As[wr * 64 + mi * 16 + lr][lg * 8]);
#pragma unroll
    for (int ni = 0; ni < 4; ++ni) bf[ni] = ld8(&Bs[wc * 64 + ni * 16 + lr][lg * 8]);
#pragma unroll
    for (int mi = 0; mi < 4; ++mi)
#pragma unroll
      for (int ni = 0; ni < 4; ++ni)
        acc[mi][ni] = mfma16x16(af[mi], bf[ni], acc[mi][ni]);
    __syncthreads();
  }
  // C/D layout: col = lane&15, row = (lane>>4)*4 + reg
#pragma unroll
  for (int mi = 0; mi < 4; ++mi)
#pragma unroll
    for (int ni = 0; ni < 4; ++ni)
#pragma unroll
      for (int r = 0; r < 4; ++r) {
        int row = m0 + wr * 64 + mi * 16 + lg * 4 + r;
        int col = n0 + wc * 64 + ni * 16 + lr;
        if constexpr (std::is_same_v<OutT, float>)
          C[(size_t)row * N + col] = acc[mi][ni][r];
        else
          C[(size_t)row * N + col] = f2b(acc[mi][ni][r]);
      }
}

// ---- V transpose: V[b][l][h*128+d] -> Vt[(b*8+h)*128+d][l] ----
__global__ __launch_bounds__(256) void k_transpose_v(const u16* __restrict__ V,
                                                     u16* __restrict__ Vt) {
  int bid = blockIdx.x;               // 32 * 2 * 16 = 1024 blocks
  int lt = bid & 31, dt = (bid >> 5) & 1, bh = bid >> 6;
  int b = bh >> 3, h = bh & 7;
  __shared__ u16 t[64][72];
#pragma unroll
  for (int i = 0; i < 16; ++i) {
    int idx = threadIdx.x + i * 256;
    int r = idx >> 6, c = idx & 63;   // r: seq row, c: depth col
    t[r][c] = V[(size_t)(b * 2048 + lt * 64 + r) * 1024 + h * 128 + dt * 64 + c];
  }
  __syncthreads();
#pragma unroll
  for (int i = 0; i < 16; ++i) {
    int idx = threadIdx.x + i * 256;
    int r = idx >> 6, c = idx & 63;   // r: depth row, c: seq col
    Vt[(size_t)(bh * 128 + dt * 64 + r) * 2048 + lt * 64 + c] = t[c][r];
  }
}

// ---- fused GQA attention, one head per block, 32 Q-rows per wave ----
// grid: 2048 = (Lq/128=16) x G=8 x B=2 x H=8 ; 256 threads = 4 waves.
// Per kt: async-stage kt+1 (global->reg before compute, reg->LDS after barrier).
// exp2-domain softmax (log2e folded into Q scale).
// Output: atomicAdd of (1/8)*O_h/l into fp32 Cacc[b][row][g*128+col].
__global__ __launch_bounds__(256) void k_attn(const u16* __restrict__ Q,
                                              const u16* __restrict__ K,
                                              const u16* __restrict__ Vt,
                                              float* __restrict__ Cacc) {
  const int bid = blockIdx.x;
  const int qt = bid & 15, g = (bid >> 4) & 7, b = (bid >> 7) & 1, h = (bid >> 8) & 7;
  const int tid = threadIdx.x, lane = tid & 63, w = tid >> 6;
  const int lr = lane & 15, lg = lane >> 4;

  __shared__ __align__(16) u16 ks[64 * 128];    // K tile,  rows=kv, cols=depth
  __shared__ __align__(16) u16 vts[128 * 64];   // Vt tile, rows=depth, cols=kv
  __shared__ __align__(16) u16 ps[4 * 32 * 64]; // per-wave P strip (32 rows)

  auto KS = [&](int row, int e) -> u16* { return &ks[row * 128 + (e ^ ((row & 7) << 3))]; };
  auto VT = [&](int row, int e) -> u16* { return &vts[row * 64 + (e ^ ((row & 7) << 3))]; };
  auto PS = [&](int ww, int row, int e) -> u16* {
    return &ps[ww * 2048 + row * 64 + (e ^ ((row & 7) << 3))];
  };

  const int q0 = qt * 128;
  const u16* Kbase = K + (size_t)b * 2048 * 1024 + h * 128;
  const u16* Vtbase = Vt + (size_t)((b * 8 + h) * 128) * 2048;

  // Q fragments in registers: rows w*32 + m*16 + lr, pre-scaled by log2e/sqrt(128)
  short8 qf[2][4];
  {
    const float sc = 0.08838834764831845f * 1.4426950408889634f;
#pragma unroll
    for (int m = 0; m < 2; ++m) {
      const u16* qp = Q + (size_t)(b * 2048 + q0 + w * 32 + m * 16 + lr) * 1024 + g * 128;
#pragma unroll
      for (int kf = 0; kf < 4; ++kf) {
        short8 v = ld8(qp + kf * 32 + lg * 8);
#pragma unroll
        for (int e = 0; e < 8; ++e) v[e] = (short)f2b(b2f((u16)v[e]) * sc);
        qf[m][kf] = v;
      }
    }
  }

  const short one_bf = (short)0x3F80;  // bf16 1.0
  const short8 ones = short8{one_bf, one_bf, one_bf, one_bf, one_bf, one_bf, one_bf, one_bf};

  f32x4 oh[2][8];
#pragma unroll
  for (int m = 0; m < 2; ++m)
#pragma unroll
    for (int f = 0; f < 8; ++f) oh[m][f] = f32x4{0.f, 0.f, 0.f, 0.f};
  f32x4 lsum[2] = {f32x4{0.f, 0.f, 0.f, 0.f}, f32x4{0.f, 0.f, 0.f, 0.f}};
  float mrun[2][4] = {{-1e30f, -1e30f, -1e30f, -1e30f}, {-1e30f, -1e30f, -1e30f, -1e30f}};

  short8 kreg[4], vreg[4];
  auto LOAD = [&](int kt) {
    const int k0 = kt * 64;
#pragma unroll
    for (int i = 0; i < 4; ++i) {
      int c = tid + i * 256;
      kreg[i] = ld8(Kbase + (size_t)(k0 + (c >> 4)) * 1024 + (c & 15) * 8);
      vreg[i] = ld8(Vtbase + (size_t)(c >> 3) * 2048 + k0 + (c & 7) * 8);
    }
  };
  auto WRITE = [&]() {
#pragma unroll
    for (int i = 0; i < 4; ++i) {
      int c = tid + i * 256;
      st8(KS(c >> 4, (c & 15) * 8), kreg[i]);
      st8(VT(c >> 3, (c & 7) * 8), vreg[i]);
    }
  };

  LOAD(0);
  WRITE();
  __syncthreads();

  for (int kt = 0; kt < 32; ++kt) {
    if (kt < 31) LOAD(kt + 1);  // issue early; lands under compute

    // S = Q(32x128) . K^T : B-fragments read once, used by both row-frags
    f32x4 s[2][4];
#pragma unroll
    for (int m = 0; m < 2; ++m)
#pragma unroll
      for (int c = 0; c < 4; ++c) s[m][c] = f32x4{0.f, 0.f, 0.f, 0.f};
#pragma unroll
    for (int c = 0; c < 4; ++c)
#pragma unroll
      for (int kf = 0; kf < 4; ++kf) {
        short8 bfr = ld8(KS(c * 16 + lr, kf * 32 + lg * 8));
        s[0][c] = mfma16x16(qf[0][kf], bfr, s[0][c]);
        s[1][c] = mfma16x16(qf[1][kf], bfr, s[1][c]);
      }

    // online softmax (exp2 domain) with defer-max (skip rescale when no growth)
    float vmax[2][4];
    bool grow = false;
#pragma unroll
    for (int m = 0; m < 2; ++m)
#pragma unroll
      for (int r = 0; r < 4; ++r) {
        float v = fmaxf(fmaxf(s[m][0][r], s[m][1][r]), fmaxf(s[m][2][r], s[m][3][r]));
#pragma unroll
        for (int off = 1; off <= 8; off <<= 1) v = fmaxf(v, __shfl_xor(v, off));
        vmax[m][r] = v;
        grow = grow || (v > mrun[m][r]);
      }
    if (__any(grow)) {
#pragma unroll
      for (int m = 0; m < 2; ++m)
#pragma unroll
        for (int r = 0; r < 4; ++r) {
          float mn = fmaxf(mrun[m][r], vmax[m][r]);
          float corr = exp2f(mrun[m][r] - mn);
          mrun[m][r] = mn;
          lsum[m][r] *= corr;
#pragma unroll
          for (int f = 0; f < 8; ++f) oh[m][f][r] *= corr;
        }
    }
#pragma unroll
    for (int m = 0; m < 2; ++m)
#pragma unroll
      for (int c = 0; c < 4; ++c)
#pragma unroll
        for (int r = 0; r < 4; ++r) {
          float p = exp2f(s[m][c][r] - mrun[m][r]);
          *PS(w, m * 16 + lg * 4 + r, c * 16 + lr) = __builtin_bit_cast(u16, (__bf16)p);
        }
    asm volatile("s_waitcnt lgkmcnt(0)" ::: "memory");
    __builtin_amdgcn_sched_barrier(0);

    short8 p0[2], p1[2];
#pragma unroll
    for (int m = 0; m < 2; ++m) {
      p0[m] = ld8(PS(w, m * 16 + lr, lg * 8));
      p1[m] = ld8(PS(w, m * 16 + lr, 32 + lg * 8));
      lsum[m] = mfma16x16(p0[m], ones, lsum[m]);
      lsum[m] = mfma16x16(p1[m], ones, lsum[m]);
    }
#pragma unroll
    for (int f = 0; f < 8; ++f) {
      short8 v0 = ld8(VT(f * 16 + lr, lg * 8));
      short8 v1 = ld8(VT(f * 16 + lr, 32 + lg * 8));
      oh[0][f] = mfma16x16(p0[0], v0, oh[0][f]);
      oh[0][f] = mfma16x16(p1[0], v1, oh[0][f]);
      oh[1][f] = mfma16x16(p0[1], v0, oh[1][f]);
      oh[1][f] = mfma16x16(p1[1], v1, oh[1][f]);
    }
    __syncthreads();            // all waves done reading LDS[kt]
    if (kt < 31) WRITE();       // reg -> LDS for kt+1
    __syncthreads();            // LDS[kt+1] visible
  }

  // atomic accumulate (1/8)*O_h/l into fp32 combined buffer
#pragma unroll
  for (int m = 0; m < 2; ++m) {
    float norm[4];
#pragma unroll
    for (int r = 0; r < 4; ++r) norm[r] = 0.125f / lsum[m][r];
    float* co = Cacc + (size_t)(b * 2048 + q0 + w * 32 + m * 16 + lg * 4) * 1024 + g * 128 + lr;
#pragma unroll
    for (int f = 0; f < 8; ++f)
#pragma unroll
      for (int r = 0; r < 4; ++r)
        atomicAdd(&co[(size_t)r * 1024 + f * 16], oh[m][f][r] * norm[r]);
  }
}

extern "C" void kernel_launch(void* const* d_in, const int* in_sizes, int n_in,
                              void* d_out, int out_size, void* d_ws, size_t ws_size,
                              hipStream_t stream) {
  const float* x_q = (const float*)d_in[0];
  const float* x_k = (const float*)d_in[1];
  const float* x_v = (const float*)d_in[2];
  const float* Wq = (const float*)d_in[3];
  const float* Wk = (const float*)d_in[4];
  const float* Wv = (const float*)d_in[5];
  const float* Wo = (const float*)d_in[6];
  float* out = (float*)d_out;

  const size_t NX = (size_t)2 * 2048 * 1024;  // 4,194,304
  const size_t NW = (size_t)1024 * 1024;      // 1,048,576
  u16* ws = (u16*)d_ws;
  // Buffer plan with reuse (58.7 MB total):
  //   [0,NX)        xqb  -> reused as Vtb (dead after Q-proj)
  //   [NX,3NX)      xkb, xvb -> reused as Cacc fp32 (NX floats = 2NX u16)
  //   [3NX,+4NW)    weights
  //   then Qb, Kb, Vb
  u16* xqb = ws;
  u16* xkb = xqb + NX;
  u16* xvb = xkb + NX;
  u16* wqb = xvb + NX;
  u16* wkb = wqb + NW;
  u16* wvb = wkb + NW;
  u16* wob = wvb + NW;
  u16* Qb  = wob + NW;
  u16* Kb  = Qb + NX;
  u16* Vb  = Kb + NX;
  u16* Vtb = xqb;            // reuse: x_q bf16 dead after Q projection
  float* Cacc = (float*)xkb; // reuse: xkb+xvb dead after K,V projections (NX floats)

  dim3 blk(256);
  k_cvt<<<dim3(NX / 1024), blk, 0, stream>>>(x_q, xqb, (int)(NX / 4));
  k_cvt<<<dim3(NX / 1024), blk, 0, stream>>>(x_k, xkb, (int)(NX / 4));
  k_cvt<<<dim3(NX / 1024), blk, 0, stream>>>(x_v, xvb, (int)(NX / 4));
  k_cvt<<<dim3(NW / 1024), blk, 0, stream>>>(Wq, wqb, (int)(NW / 4));
  k_cvt<<<dim3(NW / 1024), blk, 0, stream>>>(Wk, wkb, (int)(NW / 4));
  k_cvt<<<dim3(NW / 1024), blk, 0, stream>>>(Wv, wvb, (int)(NW / 4));
  k_cvt<<<dim3(NW / 1024), blk, 0, stream>>>(Wo, wob, (int)(NW / 4));

  dim3 ggrid(8, 32);  // N/128 x M/128
  k_gemm_nt<u16, u16><<<ggrid, blk, 0, stream>>>(xqb, wqb, Qb, 4096, 1024, 1024);
  k_gemm_nt<u16, u16><<<ggrid, blk, 0, stream>>>(xkb, wkb, Kb, 4096, 1024, 1024);
  k_gemm_nt<u16, u16><<<ggrid, blk, 0, stream>>>(xvb, wvb, Vb, 4096, 1024, 1024);

  k_transpose_v<<<dim3(1024), blk, 0, stream>>>(Vb, Vtb);

  hipMemsetAsync(Cacc, 0, NX * sizeof(float), stream);
  k_attn<<<dim3(2048), blk, 0, stream>>>(Qb, Kb, Vtb, Cacc);

  k_gemm_nt<float, float><<<ggrid, blk, 0, stream>>>(Cacc, wob, out, 4096, 1024, 1024);
}

// Round 12
// 763.374 us; speedup vs baseline: 1.6701x; 1.6701x over previous
//
#include <hip/hip_runtime.h>
#include <type_traits>
#include <utility>

// GroupQueryAttention on MI355X (gfx950), bf16 MFMA pipeline.
// B=2, Lq=Lk=2048, D_MODEL=1024, H=G=8, DEPTH=128.

using u16 = unsigned short;

typedef float f32x4 __attribute__((ext_vector_type(4)));
typedef short short8 __attribute__((ext_vector_type(8)));
typedef __bf16 bf16x8 __attribute__((ext_vector_type(8)));

#define DEV __device__ __forceinline__

// ---- MFMA wrapper: hedge the builtin's operand type (short8 vs bf16x8) ----
template <typename V, typename = void> struct MfmaTakes : std::false_type {};
template <typename V>
struct MfmaTakes<V, std::void_t<decltype(__builtin_amdgcn_mfma_f32_16x16x32_bf16(
    std::declval<V>(), std::declval<V>(), std::declval<f32x4>(), 0, 0, 0))>>
    : std::true_type {};
using mfma_ab = std::conditional_t<MfmaTakes<short8>::value, short8, bf16x8>;
static_assert(sizeof(mfma_ab) == 16, "mfma operand must be 4 VGPRs");

DEV f32x4 mfma16x16(short8 a, short8 b, f32x4 c) {
  return __builtin_amdgcn_mfma_f32_16x16x32_bf16(
      __builtin_bit_cast(mfma_ab, a), __builtin_bit_cast(mfma_ab, b), c, 0, 0, 0);
}

// ---- bf16 <-> f32 helpers (RNE) ----
DEV u16 f2b(float f) {
  unsigned u = __float_as_uint(f);
  u += 0x7fffu + ((u >> 16) & 1u);
  return (u16)(u >> 16);
}
DEV float b2f(u16 h) { return __uint_as_float(((unsigned)h) << 16); }

DEV short8 ld8(const u16* p) { return *reinterpret_cast<const short8*>(p); }
DEV void st8(u16* p, short8 v) { *reinterpret_cast<short8*>(p) = v; }

// ---- fp32 -> bf16 conversion (4 elems/thread) ----
__global__ __launch_bounds__(256) void k_cvt(const float* __restrict__ src,
                                             u16* __restrict__ dst, int n4) {
  int i = blockIdx.x * 256 + threadIdx.x;
  if (i >= n4) return;
  float4 v = reinterpret_cast<const float4*>(src)[i];
  unsigned long long r = (unsigned long long)f2b(v.x) |
                         ((unsigned long long)f2b(v.y) << 16) |
                         ((unsigned long long)f2b(v.z) << 32) |
                         ((unsigned long long)f2b(v.w) << 48);
  reinterpret_cast<unsigned long long*>(dst)[i] = r;
}

// ---- bf16 NT GEMM: C[M][N] = A[M][K] * B[N][K]^T, fp32 acc ----
// A may be bf16 (u16) or fp32 (converted in staging).
template <typename AT, typename OutT>
__global__ __launch_bounds__(256) void k_gemm_nt(const AT* __restrict__ A,
                                                 const u16* __restrict__ Bm,
                                                 OutT* __restrict__ C,
                                                 int M, int N, int K) {
  __shared__ __align__(16) u16 As[128][40];
  __shared__ __align__(16) u16 Bs[128][40];
  const int tid = threadIdx.x, lane = tid & 63, w = tid >> 6;
  const int lr = lane & 15, lg = lane >> 4;
  const int wr = w >> 1, wc = w & 1;
  const int m0 = blockIdx.y * 128, n0 = blockIdx.x * 128;

  f32x4 acc[4][4];
#pragma unroll
  for (int mi = 0; mi < 4; ++mi)
#pragma unroll
    for (int ni = 0; ni < 4; ++ni) acc[mi][ni] = f32x4{0.f, 0.f, 0.f, 0.f};

  for (int k0 = 0; k0 < K; k0 += 32) {
#pragma unroll
    for (int i = 0; i < 2; ++i) {   // 512 16B-chunks per tile, 2 per thread
      int c = tid + i * 256;
      int r = c >> 2, j = c & 3;
      short8 va;
      if constexpr (std::is_same_v<AT, float>) {
        const float* ap = A + (size_t)(m0 + r) * K + k0 + j * 8;
        float4 f0 = *reinterpret_cast<const float4*>(ap);
        float4 f1 = *reinterpret_cast<const float4*>(ap + 4);
        va = short8{(short)f2b(f0.x), (short)f2b(f0.y), (short)f2b(f0.z), (short)f2b(f0.w),
                    (short)f2b(f1.x), (short)f2b(f1.y), (short)f2b(f1.z), (short)f2b(f1.w)};
      } else {
        va = ld8(A + (size_t)(m0 + r) * K + k0 + j * 8);
      }
      short8 vb = ld8(Bm + (size_t)(n0 + r) * K + k0 + j * 8);
      st8(&As[r][j * 8], va);
      st8(&Bs[r][j * 8], vb);
    }
    __syncthreads();
    short8 af[4], bf[4];
#pragma unroll
    for (int mi = 0; mi < 4; ++mi) af[mi] = ld8(&As[wr * 64 + mi * 16 + lr][lg * 8]);
#pragma unroll
    for (int ni = 0; ni < 4; ++ni) bf[ni] = ld8(&Bs[wc * 64 + ni * 16 + lr][lg * 8]);
#pragma unroll
    for (int mi = 0; mi < 4; ++mi)
#pragma unroll
      for (int ni = 0; ni < 4; ++ni)
        acc[mi][ni] = mfma16x16(af[mi], bf[ni], acc[mi][ni]);
    __syncthreads();
  }
  // C/D layout: col = lane&15, row = (lane>>4)*4 + reg
#pragma unroll
  for (int mi = 0; mi < 4; ++mi)
#pragma unroll
    for (int ni = 0; ni < 4; ++ni)
#pragma unroll
      for (int r = 0; r < 4; ++r) {
        int row = m0 + wr * 64 + mi * 16 + lg * 4 + r;
        int col = n0 + wc * 64 + ni * 16 + lr;
        if constexpr (std::is_same_v<OutT, float>)
          C[(size_t)row * N + col] = acc[mi][ni][r];
        else
          C[(size_t)row * N + col] = f2b(acc[mi][ni][r]);
      }
}

// ---- V transpose: V[b][l][h*128+d] -> Vt[(b*8+h)*128+d][l] ----
__global__ __launch_bounds__(256) void k_transpose_v(const u16* __restrict__ V,
                                                     u16* __restrict__ Vt) {
  int bid = blockIdx.x;               // 32 * 2 * 16 = 1024 blocks
  int lt = bid & 31, dt = (bid >> 5) & 1, bh = bid >> 6;
  int b = bh >> 3, h = bh & 7;
  __shared__ u16 t[64][72];
#pragma unroll
  for (int i = 0; i < 16; ++i) {
    int idx = threadIdx.x + i * 256;
    int r = idx >> 6, c = idx & 63;   // r: seq row, c: depth col
    t[r][c] = V[(size_t)(b * 2048 + lt * 64 + r) * 1024 + h * 128 + dt * 64 + c];
  }
  __syncthreads();
#pragma unroll
  for (int i = 0; i < 16; ++i) {
    int idx = threadIdx.x + i * 256;
    int r = idx >> 6, c = idx & 63;   // r: depth row, c: seq col
    Vt[(size_t)(bh * 128 + dt * 64 + r) * 2048 + lt * 64 + c] = t[c][r];
  }
}

// ---- fused GQA attention, one head per block, 8 waves sharing one stage ----
// grid: 2048 = (Lq/128=16) x G=8 x B=2 x H=8 ; 512 threads = 8 waves, 16 Q rows/wave.
// Same per-wave shape as the 687us r10 kernel (VGPR ~92, 16 waves/CU target),
// but the 32KB K/V stage now feeds 128 Q-rows -> 2x MFMA per staged byte and
// half the staging work per thread. exp2-domain softmax (log2e folded into Q).
// Output: atomicAdd of (1/8)*O_h/l into fp32 Cacc[b][row][g*128+col].
__global__ __launch_bounds__(512) void k_attn(const u16* __restrict__ Q,
                                              const u16* __restrict__ K,
                                              const u16* __restrict__ Vt,
                                              float* __restrict__ Cacc) {
  const int bid = blockIdx.x;
  const int qt = bid & 15, g = (bid >> 4) & 7, b = (bid >> 7) & 1, h = (bid >> 8) & 7;
  const int tid = threadIdx.x, lane = tid & 63, w = tid >> 6;
  const int lr = lane & 15, lg = lane >> 4;

  __shared__ __align__(16) u16 ks[64 * 128];    // K tile,  rows=kv, cols=depth (16KB)
  __shared__ __align__(16) u16 vts[128 * 64];   // Vt tile, rows=depth, cols=kv (16KB)
  __shared__ __align__(16) u16 ps[8 * 16 * 64]; // per-wave P strip (16KB)

  auto KS = [&](int row, int e) -> u16* { return &ks[row * 128 + (e ^ ((row & 7) << 3))]; };
  auto VT = [&](int row, int e) -> u16* { return &vts[row * 64 + (e ^ ((row & 7) << 3))]; };
  auto PS = [&](int ww, int row, int e) -> u16* {
    return &ps[ww * 1024 + row * 64 + (e ^ ((row & 7) << 3))];
  };

  const int q0 = qt * 128;
  const u16* Kbase = K + (size_t)b * 2048 * 1024 + h * 128;
  const u16* Vtbase = Vt + (size_t)((b * 8 + h) * 128) * 2048;

  // Q fragments in registers: rows q0 + w*16 + lr, pre-scaled by log2e/sqrt(128)
  short8 qf[4];
  {
    const u16* qp = Q + (size_t)(b * 2048 + q0 + w * 16 + lr) * 1024 + g * 128;
    const float sc = 0.08838834764831845f * 1.4426950408889634f;
#pragma unroll
    for (int kf = 0; kf < 4; ++kf) {
      short8 v = ld8(qp + kf * 32 + lg * 8);
#pragma unroll
      for (int e = 0; e < 8; ++e) v[e] = (short)f2b(b2f((u16)v[e]) * sc);
      qf[kf] = v;
    }
  }

  const short one_bf = (short)0x3F80;  // bf16 1.0
  const short8 ones = short8{one_bf, one_bf, one_bf, one_bf, one_bf, one_bf, one_bf, one_bf};

  f32x4 oh[8];
#pragma unroll
  for (int f = 0; f < 8; ++f) oh[f] = f32x4{0.f, 0.f, 0.f, 0.f};
  f32x4 lsum = f32x4{0.f, 0.f, 0.f, 0.f};
  float mrun[4] = {-1e30f, -1e30f, -1e30f, -1e30f};

  for (int kt = 0; kt < 32; ++kt) {
    const int k0 = kt * 64;
    // stage K (64x128) and Vt (128x64): 2 chunks each per thread (512 threads)
#pragma unroll
    for (int i = 0; i < 2; ++i) {
      int c = tid + i * 512;
      st8(KS(c >> 4, (c & 15) * 8), ld8(Kbase + (size_t)(k0 + (c >> 4)) * 1024 + (c & 15) * 8));
      st8(VT(c >> 3, (c & 7) * 8), ld8(Vtbase + (size_t)(c >> 3) * 2048 + k0 + (c & 7) * 8));
    }
    __syncthreads();

    // S strip = Q(16x128) . K^T -> 4 col-fragments of 16x16
    f32x4 s[4];
#pragma unroll
    for (int c = 0; c < 4; ++c) {
      s[c] = f32x4{0.f, 0.f, 0.f, 0.f};
#pragma unroll
      for (int kf = 0; kf < 4; ++kf) {
        short8 bfr = ld8(KS(c * 16 + lr, kf * 32 + lg * 8));
        s[c] = mfma16x16(qf[kf], bfr, s[c]);
      }
    }

    // online softmax (exp2 domain) with defer-max (skip rescale when no growth)
    float vmax[4];
    bool grow = false;
#pragma unroll
    for (int r = 0; r < 4; ++r) {
      float v = fmaxf(fmaxf(s[0][r], s[1][r]), fmaxf(s[2][r], s[3][r]));
#pragma unroll
      for (int off = 1; off <= 8; off <<= 1) v = fmaxf(v, __shfl_xor(v, off));
      vmax[r] = v;
      grow = grow || (v > mrun[r]);
    }
    if (__any(grow)) {
#pragma unroll
      for (int r = 0; r < 4; ++r) {
        float mn = fmaxf(mrun[r], vmax[r]);
        float corr = exp2f(mrun[r] - mn);
        mrun[r] = mn;
        lsum[r] *= corr;
#pragma unroll
        for (int f = 0; f < 8; ++f) oh[f][r] *= corr;
      }
    }
#pragma unroll
    for (int c = 0; c < 4; ++c)
#pragma unroll
      for (int r = 0; r < 4; ++r) {
        float p = exp2f(s[c][r] - mrun[r]);
        *PS(w, lg * 4 + r, c * 16 + lr) = __builtin_bit_cast(u16, (__bf16)p);
      }
    asm volatile("s_waitcnt lgkmcnt(0)" ::: "memory");
    __builtin_amdgcn_sched_barrier(0);

    short8 p0 = ld8(PS(w, lr, lg * 8));
    short8 p1 = ld8(PS(w, lr, 32 + lg * 8));
    // row-sum via ones-B MFMA (replaces shfl sum-reduce)
    lsum = mfma16x16(p0, ones, lsum);
    lsum = mfma16x16(p1, ones, lsum);
#pragma unroll
    for (int f = 0; f < 8; ++f) {
      short8 v0 = ld8(VT(f * 16 + lr, lg * 8));
      short8 v1 = ld8(VT(f * 16 + lr, 32 + lg * 8));
      oh[f] = mfma16x16(p0, v0, oh[f]);
      oh[f] = mfma16x16(p1, v1, oh[f]);
    }
    __syncthreads();
  }

  // atomic accumulate (1/8)*O_h/l into fp32 combined buffer
  float norm[4];
#pragma unroll
  for (int r = 0; r < 4; ++r) norm[r] = 0.125f / lsum[r];
  float* co = Cacc + (size_t)(b * 2048 + q0 + w * 16 + lg * 4) * 1024 + g * 128 + lr;
#pragma unroll
  for (int f = 0; f < 8; ++f)
#pragma unroll
    for (int r = 0; r < 4; ++r)
      atomicAdd(&co[(size_t)r * 1024 + f * 16], oh[f][r] * norm[r]);
}

extern "C" void kernel_launch(void* const* d_in, const int* in_sizes, int n_in,
                              void* d_out, int out_size, void* d_ws, size_t ws_size,
                              hipStream_t stream) {
  const float* x_q = (const float*)d_in[0];
  const float* x_k = (const float*)d_in[1];
  const float* x_v = (const float*)d_in[2];
  const float* Wq = (const float*)d_in[3];
  const float* Wk = (const float*)d_in[4];
  const float* Wv = (const float*)d_in[5];
  const float* Wo = (const float*)d_in[6];
  float* out = (float*)d_out;

  const size_t NX = (size_t)2 * 2048 * 1024;  // 4,194,304
  const size_t NW = (size_t)1024 * 1024;      // 1,048,576
  u16* ws = (u16*)d_ws;
  // Buffer plan with reuse (58.7 MB total):
  //   [0,NX)        xqb  -> reused as Vtb (dead after Q-proj)
  //   [NX,3NX)      xkb, xvb -> reused as Cacc fp32 (NX floats = 2NX u16)
  //   [3NX,+4NW)    weights
  //   then Qb, Kb, Vb
  u16* xqb = ws;
  u16* xkb = xqb + NX;
  u16* xvb = xkb + NX;
  u16* wqb = xvb + NX;
  u16* wkb = wqb + NW;
  u16* wvb = wkb + NW;
  u16* wob = wvb + NW;
  u16* Qb  = wob + NW;
  u16* Kb  = Qb + NX;
  u16* Vb  = Kb + NX;
  u16* Vtb = xqb;            // reuse: x_q bf16 dead after Q projection
  float* Cacc = (float*)xkb; // reuse: xkb+xvb dead after K,V projections (NX floats)

  dim3 blk(256);
  k_cvt<<<dim3(NX / 1024), blk, 0, stream>>>(x_q, xqb, (int)(NX / 4));
  k_cvt<<<dim3(NX / 1024), blk, 0, stream>>>(x_k, xkb, (int)(NX / 4));
  k_cvt<<<dim3(NX / 1024), blk, 0, stream>>>(x_v, xvb, (int)(NX / 4));
  k_cvt<<<dim3(NW / 1024), blk, 0, stream>>>(Wq, wqb, (int)(NW / 4));
  k_cvt<<<dim3(NW / 1024), blk, 0, stream>>>(Wk, wkb, (int)(NW / 4));
  k_cvt<<<dim3(NW / 1024), blk, 0, stream>>>(Wv, wvb, (int)(NW / 4));
  k_cvt<<<dim3(NW / 1024), blk, 0, stream>>>(Wo, wob, (int)(NW / 4));

  dim3 ggrid(8, 32);  // N/128 x M/128
  k_gemm_nt<u16, u16><<<ggrid, blk, 0, stream>>>(xqb, wqb, Qb, 4096, 1024, 1024);
  k_gemm_nt<u16, u16><<<ggrid, blk, 0, stream>>>(xkb, wkb, Kb, 4096, 1024, 1024);
  k_gemm_nt<u16, u16><<<ggrid, blk, 0, stream>>>(xvb, wvb, Vb, 4096, 1024, 1024);

  k_transpose_v<<<dim3(1024), blk, 0, stream>>>(Vb, Vtb);

  hipMemsetAsync(Cacc, 0, NX * sizeof(float), stream);
  k_attn<<<dim3(2048), dim3(512), 0, stream>>>(Qb, Kb, Vtb, Cacc);

  k_gemm_nt<float, float><<<ggrid, blk, 0, stream>>>(Cacc, wob, out, 4096, 1024, 1024);
}